// Round 1
// baseline (5256.281 us; speedup 1.0000x reference)
//
#include <hip/hip_runtime.h>

typedef unsigned short u16;
typedef short bf16x8 __attribute__((ext_vector_type(8)));
typedef float f32x4 __attribute__((ext_vector_type(4)));
typedef u16 u16x8 __attribute__((ext_vector_type(8)));

#define LDA_EFF 6144
#define BD (256 * 1024)

__device__ inline u16 f2bf(float f) {
  unsigned u = __float_as_uint(f);
  unsigned r = (u + 0x7fffu + ((u >> 16) & 1u)) >> 16;
  return (u16)r;
}
__device__ inline float bf2f(u16 h) { return __uint_as_float(((unsigned)h) << 16); }

__device__ inline void gload_lds16(const u16* g, u16* l) {
  __builtin_amdgcn_global_load_lds(
      (const __attribute__((address_space(1))) void*)g,
      (__attribute__((address_space(3))) void*)l, 16, 0, 0);
}

// C[m][n] = sum_k A[m][k] * B[n][k]  (bf16 in, f32 partial out per K-split)
// BM=128, BN=64, BK=32, 256 threads, 4 waves as 2x2 (wave tile 64x32).
template <int NT, int MB, int NB>
__global__ __launch_bounds__(256) void gemm_bt(
    const u16* __restrict__ A, const u16* __restrict__ B,
    float* __restrict__ C, int lda, int ldb) {
  constexpr int BM = 128, BN = 64, BK = 32;
  constexpr int N = NB * BN;
  constexpr int KS = NT * BK;
  __shared__ u16 Ts[4][(BM + BN) * BK];

  const int bid = blockIdx.x;
  const int mb = bid % MB;
  const int nb = (bid / MB) % NB;
  const int kb = bid / (MB * NB);

  const u16* Ab = A + (mb * BM) * lda + kb * KS;
  const u16* Bb = B + (nb * BN) * ldb + kb * KS;

  const int tid = threadIdx.x;
  const int lane = tid & 63;
  const int wid = tid >> 6;
  const int wrow = (wid >> 1) * 64;
  const int wcol = (wid & 1) * 32;
  const int lr = lane & 15;
  const int lk = (lane >> 4) * 8;

  f32x4 acc[4][2];
#pragma unroll
  for (int m = 0; m < 4; m++)
#pragma unroll
    for (int n = 0; n < 2; n++) acc[m][n] = (f32x4)0.f;

  auto STAGE = [&](int buf, int kt) {
    const int base = kt * BK;
#pragma unroll
    for (int r = 0; r < (BM + BN) / 64; r++) {
      int f16 = r * 256 + tid;  // 16-byte unit index, linear in LDS
      const u16* g;
      if (f16 < BM * 4) {
        g = Ab + (f16 >> 2) * lda + base + (f16 & 3) * 8;
      } else {
        int f2 = f16 - BM * 4;
        g = Bb + (f2 >> 2) * ldb + base + (f2 & 3) * 8;
      }
      gload_lds16(g, &Ts[buf][f16 * 8]);
    }
  };

  auto COMPUTE = [&](int cur) {
    const u16* Abuf = &Ts[cur][0];
    const u16* Bbuf = &Ts[cur][BM * BK];
    bf16x8 af[4], bfr[2];
#pragma unroll
    for (int m = 0; m < 4; m++)
      af[m] = *(const bf16x8*)&Abuf[(wrow + m * 16 + lr) * BK + lk];
#pragma unroll
    for (int n = 0; n < 2; n++)
      bfr[n] = *(const bf16x8*)&Bbuf[(wcol + n * 16 + lr) * BK + lk];
#pragma unroll
    for (int m = 0; m < 4; m++)
#pragma unroll
      for (int n = 0; n < 2; n++)
        acc[m][n] = __builtin_amdgcn_mfma_f32_16x16x32_bf16(af[m], bfr[n], acc[m][n], 0, 0, 0);
  };

  // 4-buffer, depth-2 prefetch, counted vmcnt (3 loads/thread per stage).
  STAGE(0, 0);
  STAGE(1, 1);
  for (int t = 0; t < NT - 2; t++) {
    STAGE((t + 2) & 3, t + 2);
    asm volatile("s_waitcnt vmcnt(6)" ::: "memory");
    __builtin_amdgcn_s_barrier();
    COMPUTE(t & 3);
  }
  asm volatile("s_waitcnt vmcnt(3)" ::: "memory");
  __builtin_amdgcn_s_barrier();
  COMPUTE((NT - 2) & 3);
  asm volatile("s_waitcnt vmcnt(0)" ::: "memory");
  __builtin_amdgcn_s_barrier();
  COMPUTE((NT - 1) & 3);

  // Epilogue: f32 partial store. C frag layout: col=lane&15, row=(lane>>4)*4+j.
  float* Cb = C + (size_t)kb * (256 * N) + (size_t)(mb * BM + wrow) * N + nb * BN + wcol;
#pragma unroll
  for (int m = 0; m < 4; m++)
#pragma unroll
    for (int n = 0; n < 2; n++)
#pragma unroll
      for (int j = 0; j < 4; j++) {
        int row = m * 16 + (lane >> 4) * 4 + j;
        int col = n * 16 + lr;
        Cb[row * N + col] = acc[m][n][j];
      }
}

// LSTM cell update: reads 2 gates partials, writes c and h (bf16 hi/lo/hi) into A_eff.
__global__ __launch_bounds__(256) void cell_kernel(
    const float* __restrict__ g0, const float* __restrict__ g1,
    const float* __restrict__ b_ih, const float* __restrict__ b_hh,
    float* __restrict__ c, u16* __restrict__ Aeff) {
  int idx = blockIdx.x * 256 + threadIdx.x;  // 0..262143
  int b = idx >> 10, n = idx & 1023;
  int gb = b * 4096 + n;
  float xi = g0[gb] + g1[gb] + b_ih[n] + b_hh[n];
  float xf = g0[gb + 1024] + g1[gb + 1024] + b_ih[n + 1024] + b_hh[n + 1024];
  float xg = g0[gb + 2048] + g1[gb + 2048] + b_ih[n + 2048] + b_hh[n + 2048];
  float xo = g0[gb + 3072] + g1[gb + 3072] + b_ih[n + 3072] + b_hh[n + 3072];
  float ig = 1.f / (1.f + expf(-xi));
  float fg = 1.f / (1.f + expf(-xf));
  float gg = tanhf(xg);
  float og = 1.f / (1.f + expf(-xo));
  float cn = fg * c[idx] + ig * gg;
  float h = og * tanhf(cn);
  c[idx] = cn;
  u16 hi = f2bf(h);
  u16 lo = f2bf(h - bf2f(hi));
  u16* ar = Aeff + b * LDA_EFF;
  ar[3072 + n] = hi;
  ar[4096 + n] = lo;
  ar[5120 + n] = hi;
}

// y-finish: sum 8 y-partials + bias -> ys[t] (f32) and next x (bf16 hi/lo/hi) into A_eff.
__global__ __launch_bounds__(256) void yfin_kernel(
    const float* __restrict__ yp, const float* __restrict__ b_lin,
    float* __restrict__ out_t, u16* __restrict__ Aeff) {
  int idx = blockIdx.x * 256 + threadIdx.x;
  int b = idx >> 10, n = idx & 1023;
  float y = b_lin[n];
#pragma unroll
  for (int p = 0; p < 8; p++) y += yp[p * BD + idx];
  out_t[idx] = y;
  u16 hi = f2bf(y);
  u16 lo = f2bf(y - bf2f(hi));
  u16* ar = Aeff + b * LDA_EFF;
  ar[n] = hi;
  ar[1024 + n] = lo;
  ar[2048 + n] = hi;
}

// Build B_eff (4096 x 6144): [Wih_hi|Wih_hi|Wih_lo|Whh_hi|Whh_hi|Whh_lo]
__global__ __launch_bounds__(256) void prep_w1(
    const float* __restrict__ Wih, const float* __restrict__ Whh,
    u16* __restrict__ Beff) {
  int i8 = blockIdx.x * 256 + threadIdx.x;  // 0..3145727 (8 elems each)
  int j = i8 / 768, r8 = i8 % 768;
  int sec = r8 >> 7, k8 = (r8 & 127) << 3;
  const float* src = ((sec < 3) ? Wih : Whh) + j * 1024 + k8;
  bool lo = (sec == 2 || sec == 5);
  u16x8 o;
#pragma unroll
  for (int e = 0; e < 8; e++) {
    float f = src[e];
    u16 hi = f2bf(f);
    o[e] = lo ? f2bf(f - bf2f(hi)) : hi;
  }
  *(u16x8*)&Beff[(size_t)i8 * 8] = o;
}

// Build B2_eff (1024 x 3072): [Wlin_hi|Wlin_hi|Wlin_lo]
__global__ __launch_bounds__(256) void prep_w2(
    const float* __restrict__ Wlin, u16* __restrict__ B2eff) {
  int i8 = blockIdx.x * 256 + threadIdx.x;  // 0..393215
  int j = i8 / 384, r8 = i8 % 384;
  int sec = r8 >> 7, k8 = (r8 & 127) << 3;
  const float* src = Wlin + j * 1024 + k8;
  bool lo = (sec == 2);
  u16x8 o;
#pragma unroll
  for (int e = 0; e < 8; e++) {
    float f = src[e];
    u16 hi = f2bf(f);
    o[e] = lo ? f2bf(f - bf2f(hi)) : hi;
  }
  *(u16x8*)&B2eff[(size_t)i8 * 8] = o;
}

// Init A_eff = [x_hi|x_lo|x_hi|h_hi|h_lo|h_hi] from inputs/h0, and c from c0.
__global__ __launch_bounds__(256) void prep_state(
    const float* __restrict__ x0, const float* __restrict__ h0,
    const float* __restrict__ c0, u16* __restrict__ Aeff, float* __restrict__ c) {
  int i8 = blockIdx.x * 256 + threadIdx.x;  // 0..196607
  int b = i8 / 768, r8 = i8 % 768;
  int sec = r8 >> 7, k8 = (r8 & 127) << 3;
  const float* src = ((sec < 3) ? x0 : h0) + b * 1024 + k8;
  bool lo = (sec == 1 || sec == 4);
  u16x8 o;
#pragma unroll
  for (int e = 0; e < 8; e++) {
    float f = src[e];
    u16 hi = f2bf(f);
    o[e] = lo ? f2bf(f - bf2f(hi)) : hi;
  }
  *(u16x8*)&Aeff[(size_t)i8 * 8] = o;
  if (i8 < 32768) {
    float4 v0 = *(const float4*)&c0[i8 * 8];
    float4 v1 = *(const float4*)&c0[i8 * 8 + 4];
    *(float4*)&c[i8 * 8] = v0;
    *(float4*)&c[i8 * 8 + 4] = v1;
  }
}

// In-place BatchNorm over batch axis: per (t,d), mean/var over b (biased), eps=1e-5.
__global__ __launch_bounds__(256) void bn_kernel(float* __restrict__ out) {
  int t = blockIdx.x >> 2;
  int d = ((blockIdx.x & 3) << 8) + threadIdx.x;
  float* base = out + (size_t)t * BD + d;
  float s = 0.f;
  for (int b = 0; b < 256; b++) s += base[b * 1024];
  float mean = s * (1.f / 256.f);
  float vs = 0.f;
  for (int b = 0; b < 256; b++) {
    float x = base[b * 1024] - mean;
    vs += x * x;
  }
  float rstd = rsqrtf(vs * (1.f / 256.f) + 1e-5f);
  for (int b = 0; b < 256; b++) base[b * 1024] = (base[b * 1024] - mean) * rstd;
}

extern "C" void kernel_launch(void* const* d_in, const int* in_sizes, int n_in,
                              void* d_out, int out_size, void* d_ws, size_t ws_size,
                              hipStream_t stream) {
  const float* inputs = (const float*)d_in[0];
  const float* W_ih = (const float*)d_in[1];
  const float* W_hh = (const float*)d_in[2];
  const float* b_ih = (const float*)d_in[3];
  const float* b_hh = (const float*)d_in[4];
  const float* W_lin = (const float*)d_in[5];
  const float* b_lin = (const float*)d_in[6];
  const float* h0 = (const float*)d_in[7];
  const float* c0 = (const float*)d_in[8];
  float* out = (float*)d_out;

  char* ws = (char*)d_ws;
  u16* Beff = (u16*)ws;                         // 4096*6144*2  = 50,331,648
  u16* B2eff = (u16*)(ws + 50331648);           // 1024*3072*2  =  6,291,456
  u16* Aeff = (u16*)(ws + 56623104);            // 256*6144*2   =  3,145,728
  float* cbuf = (float*)(ws + 59768832);        // 256*1024*4   =  1,048,576
  float* gates = (float*)(ws + 60817408);       // 2*256*4096*4 =  8,388,608
  float* ybuf = (float*)(ws + 69206016);        // 8*256*1024*4 =  8,388,608

  prep_w1<<<12288, 256, 0, stream>>>(W_ih, W_hh, Beff);
  prep_w2<<<1536, 256, 0, stream>>>(W_lin, B2eff);
  prep_state<<<768, 256, 0, stream>>>(inputs, h0, c0, Aeff, cbuf);

  for (int t = 0; t < 128; t++) {
    // gates partials: K=6144 split in 2 (x-part / h-part), N=4096
    gemm_bt<96, 2, 64><<<256, 256, 0, stream>>>(Aeff, Beff, gates, 6144, 6144);
    cell_kernel<<<1024, 256, 0, stream>>>(gates, gates + 1048576, b_ih, b_hh, cbuf, Aeff);
    // y partials: A = h-triple (A_eff cols 3072..6143), K=3072 split in 8, N=1024
    gemm_bt<12, 2, 16><<<256, 256, 0, stream>>>(Aeff + 3072, B2eff, ybuf, 6144, 3072);
    yfin_kernel<<<1024, 256, 0, stream>>>(ybuf, b_lin, out + (size_t)t * BD, Aeff);
  }
  bn_kernel<<<512, 256, 0, stream>>>(out);
}